// Round 1
// baseline (923.285 us; speedup 1.0000x reference)
//
#include <hip/hip_runtime.h>
#include <math.h>

static constexpr float kThresh = 0.8f;

// One 32-lane half-wave per row (D=128 = 32 x float4). Lanes 0-31 -> row r,
// lanes 32-63 -> row r+1, so a full wave64 reads 1 KiB contiguous per array.
__global__ __launch_bounds__(256) void antonymy_loss_kernel(
    const float4* __restrict__ s2, const float4* __restrict__ a1,
    const float* __restrict__ score, float* __restrict__ out,
    int B, float inv_B)
{
    const int tid      = blockIdx.x * blockDim.x + threadIdx.x;
    const int lane     = threadIdx.x & 31;
    const int half_id  = tid >> 5;
    const int n_halves = (gridDim.x * blockDim.x) >> 5;

    float local = 0.0f;
    for (int r = half_id; r < B; r += n_halves) {
        const long base = (long)r * 32 + lane;   // float4 index
        float4 a = a1[base];
        float4 s = s2[base];
        float dx = a.x - s.x;
        float dy = a.y - s.y;
        float dz = a.z - s.z;
        float dw = a.w - s.w;
        float v = dx*dx + dy*dy + dz*dz + dw*dw;
        // butterfly sum across the 32 lanes of this half-wave (masks < 32
        // stay inside the half)
        v += __shfl_xor(v, 16);
        v += __shfl_xor(v, 8);
        v += __shfl_xor(v, 4);
        v += __shfl_xor(v, 2);
        v += __shfl_xor(v, 1);
        if (lane == 0) {
            float d = sqrtf(v);
            float t = tanhf(d);            // t in [0,1) since d >= 0
            float e = (score[r] >= kThresh) ? fmaxf(1.0f - t, 0.0f)
                                            : fmaxf(1.0f + t, 0.0f);
            local += e;
        }
    }

    // only lanes 0 and 32 carry nonzero 'local'; one xor-32 gives lane 0 the
    // wave total
    local += __shfl_xor(local, 32);

    __shared__ float wsum[4];
    const int wid = threadIdx.x >> 6;
    if ((threadIdx.x & 63) == 0) wsum[wid] = local;
    __syncthreads();
    if (threadIdx.x == 0) {
        float s = (wsum[0] + wsum[1]) + (wsum[2] + wsum[3]);
        atomicAdd(out, s * inv_B);   // pre-scaled: running atomic sum stays ~1
    }
}

extern "C" void kernel_launch(void* const* d_in, const int* in_sizes, int n_in,
                              void* d_out, int out_size, void* d_ws, size_t ws_size,
                              hipStream_t stream) {
    const float* s2 = (const float*)d_in[0];
    const float* a1 = (const float*)d_in[1];
    const float* sc = (const float*)d_in[2];
    float* out = (float*)d_out;
    const int B = in_sizes[2];           // 1,000,000 rows; D = in_sizes[0]/B = 128

    // d_out is poisoned 0xAA before every timed launch -> zero it (async,
    // graph-capture-safe)
    hipMemsetAsync(d_out, 0, sizeof(float), stream);

    const int blocks = 2048;             // 16384 half-waves, ~61 rows each
    antonymy_loss_kernel<<<blocks, 256, 0, stream>>>(
        (const float4*)s2, (const float4*)a1, sc, out, B, 1.0f / (float)B);
}